// Round 6
// baseline (636.431 us; speedup 1.0000x reference)
//
#include <hip/hip_runtime.h>

// Problem constants (fixed by the reference module)
#define IMG_H 1024
#define IMG_W 1024
#define NPIX (IMG_H * IMG_W)
#define N_MASKS 32
#define N_WINDOWS 4
#define MPW 8          // N_MASKS / N_WINDOWS
#define WIN_H 512
#define WIN_W 512
#define SIM_THRESH 0.1f
#define NBLK 1024
#define MAGIC 0x13579BDFu

// Native 4-float vector for __builtin_nontemporal_store (HIP float4 is a class)
typedef float vf4 __attribute__((ext_vector_type(4)));

// ws layout (uint32 words):
//   edges[32] @ 0   : 8 border blocks x 4 partial masks (L,R,T,B)
//   bflag[8]  @ 32  : border-block done flags (MAGIC)
//   locg[32]  @ 48  : channel remap
//   lflag[1]  @ 80  : loc done flag (MAGIC)
// 0xAA poison != MAGIC => replay-safe without an init dispatch.
//
// NOTE: no min-waves clamp in __launch_bounds__ — R5 showed (256,4) caps
// VGPRs at 64 and the streaming loop spills ~32 MB to scratch (WRITE_SIZE
// 158 MB vs 128.5 needed, VALUBusy 1%, 531 us). Producer blocks 0..8 are
// dispatched first into an empty machine, so co-residency of consumers is
// not required for handshake progress.

__global__ __launch_bounds__(256) void k_fused(const float* __restrict__ masks,
                                               const float* __restrict__ sf,
                                               const int* __restrict__ pl,
                                               const int* __restrict__ pt,
                                               unsigned* __restrict__ ws,
                                               float* __restrict__ out) {
    unsigned* edges = ws;        // 32 words
    unsigned* bflag = ws + 32;   // 8 words
    unsigned* locg  = ws + 48;   // 32 words
    unsigned* lflag = ws + 80;   // 1 word

    __shared__ int spl[4], spt[4];
    __shared__ unsigned segmask[2];
    __shared__ int sloc[32];
    __shared__ float sfn[28 * 65];          // stride-65: no bank conflicts
    __shared__ unsigned step_word[512];     // ci | cj<<8 | hz<<16 | pass<<17
    __shared__ unsigned fedge[4];
    __shared__ int sP;

    const int tid = threadIdx.x;
    const int lane = tid & 63;
    const int wave = tid >> 6;
    const int b = blockIdx.x;

    if (tid < 4) { spl[tid] = pl[tid]; spt[tid] = pt[tid]; }
    if (tid < 2) segmask[tid] = 0u;
    __syncthreads();

    // ---------------- special duties (blocks 0..8) ----------------
    if (b < 8) {
        // Border duty: segments 2b, 2b+1. seg s: wi = s>>2, side = s&3 (L,R,T,B)
        for (int k = 0; k < 2; k++) {
            const int s = 2 * b + k;
            const int wi = s >> 2, side = s & 3;
            const int xs = max(spl[wi], 0), xe = min(spl[wi] + WIN_W, IMG_W);
            const int ys = max(spt[wi], 0), ye = min(spt[wi] + WIN_H, IMG_H);
            if (ys >= ye || xs >= xe) continue;
            const int L = (side < 2) ? (ye - ys) : (xe - xs);
            for (int u = tid; u < L; u += 256) {
                int x, y;
                if      (side == 0) { x = xs;     y = ys + u; }
                else if (side == 1) { x = xe - 1; y = ys + u; }
                else if (side == 2) { y = ys;     x = xs + u; }
                else                { y = ye - 1; x = xs + u; }
                const int p = y * IMG_W + x;
                float bv = masks[p];
                int bc = 0;
#pragma unroll
                for (int c = 1; c < N_MASKS; c++) {
                    const float v = masks[(size_t)c * NPIX + p];
                    if (v > bv) { bv = v; bc = c; }
                }
                if ((bc >> 3) == wi) atomicOr(&segmask[k], 1u << bc);
            }
        }
        __syncthreads();
        if (tid == 0) {
            unsigned e[4] = {0u, 0u, 0u, 0u};
            e[(2 * b) & 3]     |= segmask[0];
            e[(2 * b + 1) & 3] |= segmask[1];
#pragma unroll
            for (int i = 0; i < 4; i++)
                __hip_atomic_store(&edges[4 * b + i], e[i],
                                   __ATOMIC_RELAXED, __HIP_MEMORY_SCOPE_AGENT);
            __hip_atomic_store(&bflag[b], MAGIC,
                               __ATOMIC_RELEASE, __HIP_MEMORY_SCOPE_AGENT);
        }
    } else if (b == 8) {
        // Loc duty: wait for 8 border flags, then merge decision.
        if (tid < 8) {
            while (__hip_atomic_load(&bflag[tid], __ATOMIC_ACQUIRE,
                                     __HIP_MEMORY_SCOPE_AGENT) != MAGIC)
                __builtin_amdgcn_s_sleep(8);
        }
        __syncthreads();
        if (tid == 0) {
            unsigned e0 = 0, e1 = 0, e2 = 0, e3 = 0;
            for (int i = 0; i < 8; i++) {
                e0 |= __hip_atomic_load(&edges[4 * i + 0], __ATOMIC_RELAXED, __HIP_MEMORY_SCOPE_AGENT);
                e1 |= __hip_atomic_load(&edges[4 * i + 1], __ATOMIC_RELAXED, __HIP_MEMORY_SCOPE_AGENT);
                e2 |= __hip_atomic_load(&edges[4 * i + 2], __ATOMIC_RELAXED, __HIP_MEMORY_SCOPE_AGENT);
                e3 |= __hip_atomic_load(&edges[4 * i + 3], __ATOMIC_RELAXED, __HIP_MEMORY_SCOPE_AGENT);
            }
            fedge[0] = e0; fedge[1] = e1; fedge[2] = e2; fedge[3] = e3;
        }
        // normalize slot features: x / (||x|| + 1e-8), 4 waves x 7 rows
#pragma unroll
        for (int i = 0; i < 7; i++) {
            const int r = wave + 4 * i;
            const float v = sf[r * 64 + lane];
            float s2 = v * v;
#pragma unroll
            for (int off = 1; off < 64; off <<= 1) s2 += __shfl_xor(s2, off);
            sfn[r * 65 + lane] = v * (1.0f / (sqrtf(s2) + 1e-8f));
        }
        __syncthreads();
        if (tid == 0) {
            int lpl[4], lpt[4];
            for (int i = 0; i < 4; i++) { lpl[i] = spl[i]; lpt[i] = spt[i]; }
            int aI[8], aJ[8], aH[8], na = 0;
            for (int i = 0; i < N_WINDOWS; i++)
                for (int j = i + 1; j < N_WINDOWS; j++) {
                    if (lpt[i] == lpt[j] && abs(lpl[i] - lpl[j]) == WIN_W) {
                        if (lpl[i] < lpl[j]) { aI[na] = i; aJ[na] = j; }
                        else                 { aI[na] = j; aJ[na] = i; }
                        aH[na] = 1; na++;
                    }
                    if (lpl[i] == lpl[j] && abs(lpt[i] - lpt[j]) == WIN_H) {
                        if (lpt[i] < lpt[j]) { aI[na] = i; aJ[na] = j; }
                        else                 { aI[na] = j; aJ[na] = i; }
                        aH[na] = 0; na++;
                    }
                }
            int P = 0;
            for (int a = 0; a < na; a++)
                for (int ci = aI[a] * MPW + 1; ci < (aI[a] + 1) * MPW; ci++)
                    for (int cj = aJ[a] * MPW + 1; cj < (aJ[a] + 1) * MPW; cj++)
                        step_word[P++] = (unsigned)ci | ((unsigned)cj << 8)
                                       | ((unsigned)aH[a] << 16);
            sP = P;
        }
        __syncthreads();
        const int P = sP;
        {
            const unsigned gel = fedge[0], ger = fedge[1], get = fedge[2], geb = fedge[3];
            for (int p = tid; p < P; p += 256) {
                const unsigned w = step_word[p];
                const int ci = w & 255, cj = (w >> 8) & 255, hz = (w >> 16) & 1;
                const float* fi = &sfn[((ci >> 3) * (MPW - 1) + (ci & 7) - 1) * 65];
                const float* fj = &sfn[((cj >> 3) * (MPW - 1) + (cj & 7) - 1) * 65];
                float s = 0.f;
#pragma unroll
                for (int k2 = 0; k2 < 64; k2++) s += fi[k2] * fj[k2];
                const bool eok = hz ? (((ger >> ci) & 1u) && ((gel >> cj) & 1u))
                                    : (((geb >> ci) & 1u) && ((get >> cj) & 1u));
                if (eok && s > SIM_THRESH) step_word[p] = w | (1u << 17);
            }
        }
        __syncthreads();
        if (wave == 0) {
            unsigned merged = 0;
            int myloc = lane;
            for (int p = 0; p < P; p++) {
                const unsigned w = step_word[p];
                if (w >> 17) {
                    const int ci = w & 255, cj = (w >> 8) & 255;
                    if (!((merged >> ci) & 1u) && !((merged >> cj) & 1u)) {
                        const int keep = min(ci, cj), rem = max(ci, cj);
                        if (myloc == rem) myloc = keep;
                        merged |= 1u << rem;
                    }
                }
            }
            if (lane < 32)
                __hip_atomic_store(&locg[lane], (unsigned)myloc,
                                   __ATOMIC_RELAXED, __HIP_MEMORY_SCOPE_AGENT);
        }
        __syncthreads();
        if (tid == 0) {
            __threadfence();    // order the whole workgroup's loc stores
            __hip_atomic_store(lflag, MAGIC, __ATOMIC_RELEASE, __HIP_MEMORY_SCOPE_AGENT);
        }
    }

    // ---------------- streaming: argmax of own row (ids stay in registers) ----
    const int idx = (b * 256 + tid) * 4;    // exact fit: 1024 blocks x 1024 px
    float bv0, bv1, bv2, bv3;
    int bc0 = 0, bc1 = 0, bc2 = 0, bc3 = 0;
    {
        const float4 v = *(const float4*)(masks + idx);
        bv0 = v.x; bv1 = v.y; bv2 = v.z; bv3 = v.w;
    }
#pragma unroll
    for (int c = 1; c < N_MASKS; c++) {
        const float4 v = *(const float4*)(masks + (size_t)c * NPIX + idx);
        if (v.x > bv0) { bv0 = v.x; bc0 = c; }
        if (v.y > bv1) { bv1 = v.y; bc1 = c; }
        if (v.z > bv2) { bv2 = v.z; bc2 = c; }
        if (v.w > bv3) { bv3 = v.w; bc3 = c; }
    }

    // ---------------- wait for loc (long since published by now) -------------
    if (tid == 0) {
        while (__hip_atomic_load(lflag, __ATOMIC_ACQUIRE,
                                 __HIP_MEMORY_SCOPE_AGENT) != MAGIC)
            __builtin_amdgcn_s_sleep(8);
    }
    __syncthreads();
    if (tid < 32)
        sloc[tid] = (int)__hip_atomic_load(&locg[tid], __ATOMIC_RELAXED,
                                           __HIP_MEMORY_SCOPE_AGENT);
    __syncthreads();

    // ---------------- write one-hot output (nontemporal float4) --------------
    const int r0 = sloc[bc0], r1 = sloc[bc1], r2 = sloc[bc2], r3 = sloc[bc3];
#pragma unroll
    for (int c = 0; c < N_MASKS; c++) {
        vf4 v;
        v.x = (r0 == c) ? 1.0f : 0.0f;
        v.y = (r1 == c) ? 1.0f : 0.0f;
        v.z = (r2 == c) ? 1.0f : 0.0f;
        v.w = (r3 == c) ? 1.0f : 0.0f;
        __builtin_nontemporal_store(v, (vf4*)(out + (size_t)c * NPIX + idx));
    }
}

extern "C" void kernel_launch(void* const* d_in, const int* in_sizes, int n_in,
                              void* d_out, int out_size, void* d_ws, size_t ws_size,
                              hipStream_t stream) {
    const float* masks = (const float*)d_in[0];   // (1, 32, 1024, 1024) f32
    const float* sf    = (const float*)d_in[1];   // (4, 7, 64) f32
    const int*   pl    = (const int*)d_in[2];     // (4,) i32
    const int*   pt    = (const int*)d_in[3];     // (4,) i32
    float* out = (float*)d_out;
    unsigned* ws = (unsigned*)d_ws;

    k_fused<<<NBLK, 256, 0, stream>>>(masks, sf, pl, pt, ws, out);
}

// Round 7
// 320.460 us; speedup vs baseline: 1.9860x; 1.9860x over previous
//
#include <hip/hip_runtime.h>

// Problem constants (fixed by the reference module)
#define IMG_H 1024
#define IMG_W 1024
#define NPIX (IMG_H * IMG_W)
#define N_MASKS 32
#define N_WINDOWS 4
#define MPW 8          // N_MASKS / N_WINDOWS
#define WIN_H 512
#define WIN_W 512
#define SIM_THRESH 0.1f
#define NBLK 1024
#define MAGIC 0x13579BDFu

// Native 4-float vector for __builtin_nontemporal_store (HIP float4 is a class)
typedef float vf4 __attribute__((ext_vector_type(4)));

// ws layout (uint32 words):
//   edges[32] @ 0   : 8 border blocks x 4 partial masks (L,R,T,B)
//   bflag[8]  @ 32  : border-block done flags (MAGIC)
//   locg[32]  @ 48  : channel remap
//   lflag[1]  @ 80  : loc done flag (MAGIC)
// 0xAA poison != MAGIC => replay-safe without an init dispatch.
//
// Lessons encoded here:
//  - R5: __launch_bounds__(256,4) forced VGPR=64 -> ~32 MB scratch spills
//    (WRITE 158 MB). Use plain (256).
//  - R6: ACQUIRE polling loads emit a cache invalidate PER POLL; 1024
//    pollers thrash every XCD's caches while others stream (430 GB/s,
//    VALUBusy 1%, 490 us). Poll with RELAXED atomic loads (uncached read
//    of the coherence point, no invalidate); producers use one-shot
//    RELEASE stores; cross-block data (edges/locg) read via RELAXED
//    agent-scope atomic loads which bypass the non-coherent caches.

__global__ __launch_bounds__(256) void k_fused(const float* __restrict__ masks,
                                               const float* __restrict__ sf,
                                               const int* __restrict__ pl,
                                               const int* __restrict__ pt,
                                               unsigned* __restrict__ ws,
                                               float* __restrict__ out) {
    unsigned* edges = ws;        // 32 words
    unsigned* bflag = ws + 32;   // 8 words
    unsigned* locg  = ws + 48;   // 32 words
    unsigned* lflag = ws + 80;   // 1 word

    __shared__ int spl[4], spt[4];
    __shared__ unsigned segmask[2];
    __shared__ int sloc[32];
    __shared__ float sfn[28 * 65];          // stride-65: no bank conflicts
    __shared__ unsigned step_word[512];     // ci | cj<<8 | hz<<16 | pass<<17
    __shared__ unsigned fedge[4];
    __shared__ int sP;

    const int tid = threadIdx.x;
    const int lane = tid & 63;
    const int wave = tid >> 6;
    const int b = blockIdx.x;

    if (tid < 4) { spl[tid] = pl[tid]; spt[tid] = pt[tid]; }
    if (tid < 2) segmask[tid] = 0u;
    __syncthreads();

    // ---------------- special duties (blocks 0..8) ----------------
    if (b < 8) {
        // Border duty: segments 2b, 2b+1. seg s: wi = s>>2, side = s&3 (L,R,T,B)
        for (int k = 0; k < 2; k++) {
            const int s = 2 * b + k;
            const int wi = s >> 2, side = s & 3;
            const int xs = max(spl[wi], 0), xe = min(spl[wi] + WIN_W, IMG_W);
            const int ys = max(spt[wi], 0), ye = min(spt[wi] + WIN_H, IMG_H);
            if (ys >= ye || xs >= xe) continue;
            const int L = (side < 2) ? (ye - ys) : (xe - xs);
            for (int u = tid; u < L; u += 256) {
                int x, y;
                if      (side == 0) { x = xs;     y = ys + u; }
                else if (side == 1) { x = xe - 1; y = ys + u; }
                else if (side == 2) { y = ys;     x = xs + u; }
                else                { y = ye - 1; x = xs + u; }
                const int p = y * IMG_W + x;
                float bv = masks[p];
                int bc = 0;
#pragma unroll
                for (int c = 1; c < N_MASKS; c++) {
                    const float v = masks[(size_t)c * NPIX + p];
                    if (v > bv) { bv = v; bc = c; }
                }
                if ((bc >> 3) == wi) atomicOr(&segmask[k], 1u << bc);
            }
        }
        __syncthreads();
        if (tid == 0) {
            unsigned e[4] = {0u, 0u, 0u, 0u};
            e[(2 * b) & 3]     |= segmask[0];
            e[(2 * b + 1) & 3] |= segmask[1];
#pragma unroll
            for (int i = 0; i < 4; i++)
                __hip_atomic_store(&edges[4 * b + i], e[i],
                                   __ATOMIC_RELAXED, __HIP_MEMORY_SCOPE_AGENT);
            __hip_atomic_store(&bflag[b], MAGIC,
                               __ATOMIC_RELEASE, __HIP_MEMORY_SCOPE_AGENT);
        }
    } else if (b == 8) {
        // Loc duty: wait for 8 border flags (RELAXED polls — no invalidates).
        if (tid < 8) {
            while (__hip_atomic_load(&bflag[tid], __ATOMIC_RELAXED,
                                     __HIP_MEMORY_SCOPE_AGENT) != MAGIC)
                __builtin_amdgcn_s_sleep(8);
        }
        __syncthreads();
        if (tid == 0) {
            unsigned e0 = 0, e1 = 0, e2 = 0, e3 = 0;
            for (int i = 0; i < 8; i++) {
                e0 |= __hip_atomic_load(&edges[4 * i + 0], __ATOMIC_RELAXED, __HIP_MEMORY_SCOPE_AGENT);
                e1 |= __hip_atomic_load(&edges[4 * i + 1], __ATOMIC_RELAXED, __HIP_MEMORY_SCOPE_AGENT);
                e2 |= __hip_atomic_load(&edges[4 * i + 2], __ATOMIC_RELAXED, __HIP_MEMORY_SCOPE_AGENT);
                e3 |= __hip_atomic_load(&edges[4 * i + 3], __ATOMIC_RELAXED, __HIP_MEMORY_SCOPE_AGENT);
            }
            fedge[0] = e0; fedge[1] = e1; fedge[2] = e2; fedge[3] = e3;
        }
        // normalize slot features: x / (||x|| + 1e-8), 4 waves x 7 rows
#pragma unroll
        for (int i = 0; i < 7; i++) {
            const int r = wave + 4 * i;
            const float v = sf[r * 64 + lane];
            float s2 = v * v;
#pragma unroll
            for (int off = 1; off < 64; off <<= 1) s2 += __shfl_xor(s2, off);
            sfn[r * 65 + lane] = v * (1.0f / (sqrtf(s2) + 1e-8f));
        }
        __syncthreads();
        if (tid == 0) {
            int lpl[4], lpt[4];
            for (int i = 0; i < 4; i++) { lpl[i] = spl[i]; lpt[i] = spt[i]; }
            int aI[8], aJ[8], aH[8], na = 0;
            for (int i = 0; i < N_WINDOWS; i++)
                for (int j = i + 1; j < N_WINDOWS; j++) {
                    if (lpt[i] == lpt[j] && abs(lpl[i] - lpl[j]) == WIN_W) {
                        if (lpl[i] < lpl[j]) { aI[na] = i; aJ[na] = j; }
                        else                 { aI[na] = j; aJ[na] = i; }
                        aH[na] = 1; na++;
                    }
                    if (lpl[i] == lpl[j] && abs(lpt[i] - lpt[j]) == WIN_H) {
                        if (lpt[i] < lpt[j]) { aI[na] = i; aJ[na] = j; }
                        else                 { aI[na] = j; aJ[na] = i; }
                        aH[na] = 0; na++;
                    }
                }
            int P = 0;
            for (int a = 0; a < na; a++)
                for (int ci = aI[a] * MPW + 1; ci < (aI[a] + 1) * MPW; ci++)
                    for (int cj = aJ[a] * MPW + 1; cj < (aJ[a] + 1) * MPW; cj++)
                        step_word[P++] = (unsigned)ci | ((unsigned)cj << 8)
                                       | ((unsigned)aH[a] << 16);
            sP = P;
        }
        __syncthreads();
        const int P = sP;
        {
            const unsigned gel = fedge[0], ger = fedge[1], get = fedge[2], geb = fedge[3];
            for (int p = tid; p < P; p += 256) {
                const unsigned w = step_word[p];
                const int ci = w & 255, cj = (w >> 8) & 255, hz = (w >> 16) & 1;
                const float* fi = &sfn[((ci >> 3) * (MPW - 1) + (ci & 7) - 1) * 65];
                const float* fj = &sfn[((cj >> 3) * (MPW - 1) + (cj & 7) - 1) * 65];
                float s = 0.f;
#pragma unroll
                for (int k2 = 0; k2 < 64; k2++) s += fi[k2] * fj[k2];
                const bool eok = hz ? (((ger >> ci) & 1u) && ((gel >> cj) & 1u))
                                    : (((geb >> ci) & 1u) && ((get >> cj) & 1u));
                if (eok && s > SIM_THRESH) step_word[p] = w | (1u << 17);
            }
        }
        __syncthreads();
        if (wave == 0) {
            unsigned merged = 0;
            int myloc = lane;
            for (int p = 0; p < P; p++) {
                const unsigned w = step_word[p];
                if (w >> 17) {
                    const int ci = w & 255, cj = (w >> 8) & 255;
                    if (!((merged >> ci) & 1u) && !((merged >> cj) & 1u)) {
                        const int keep = min(ci, cj), rem = max(ci, cj);
                        if (myloc == rem) myloc = keep;
                        merged |= 1u << rem;
                    }
                }
            }
            if (lane < 32)
                __hip_atomic_store(&locg[lane], (unsigned)myloc,
                                   __ATOMIC_RELAXED, __HIP_MEMORY_SCOPE_AGENT);
        }
        __syncthreads();
        if (tid == 0) {
            __threadfence();    // order the whole workgroup's loc stores
            __hip_atomic_store(lflag, MAGIC, __ATOMIC_RELEASE, __HIP_MEMORY_SCOPE_AGENT);
        }
    }

    // ---------------- streaming: argmax of own row (ids stay in registers) ----
    const int idx = (b * 256 + tid) * 4;    // exact fit: 1024 blocks x 1024 px
    float bv0, bv1, bv2, bv3;
    int bc0 = 0, bc1 = 0, bc2 = 0, bc3 = 0;
    {
        const float4 v = *(const float4*)(masks + idx);
        bv0 = v.x; bv1 = v.y; bv2 = v.z; bv3 = v.w;
    }
#pragma unroll
    for (int c = 1; c < N_MASKS; c++) {
        const float4 v = *(const float4*)(masks + (size_t)c * NPIX + idx);
        if (v.x > bv0) { bv0 = v.x; bc0 = c; }
        if (v.y > bv1) { bv1 = v.y; bc1 = c; }
        if (v.z > bv2) { bv2 = v.z; bc2 = c; }
        if (v.w > bv3) { bv3 = v.w; bc3 = c; }
    }

    // ---------------- wait for loc (RELAXED poll — no cache invalidates) -----
    if (tid == 0) {
        while (__hip_atomic_load(lflag, __ATOMIC_RELAXED,
                                 __HIP_MEMORY_SCOPE_AGENT) != MAGIC)
            __builtin_amdgcn_s_sleep(32);
    }
    __syncthreads();
    if (tid < 32)
        sloc[tid] = (int)__hip_atomic_load(&locg[tid], __ATOMIC_RELAXED,
                                           __HIP_MEMORY_SCOPE_AGENT);
    __syncthreads();

    // ---------------- write one-hot output (nontemporal float4) --------------
    const int r0 = sloc[bc0], r1 = sloc[bc1], r2 = sloc[bc2], r3 = sloc[bc3];
#pragma unroll
    for (int c = 0; c < N_MASKS; c++) {
        vf4 v;
        v.x = (r0 == c) ? 1.0f : 0.0f;
        v.y = (r1 == c) ? 1.0f : 0.0f;
        v.z = (r2 == c) ? 1.0f : 0.0f;
        v.w = (r3 == c) ? 1.0f : 0.0f;
        __builtin_nontemporal_store(v, (vf4*)(out + (size_t)c * NPIX + idx));
    }
}

extern "C" void kernel_launch(void* const* d_in, const int* in_sizes, int n_in,
                              void* d_out, int out_size, void* d_ws, size_t ws_size,
                              hipStream_t stream) {
    const float* masks = (const float*)d_in[0];   // (1, 32, 1024, 1024) f32
    const float* sf    = (const float*)d_in[1];   // (4, 7, 64) f32
    const int*   pl    = (const int*)d_in[2];     // (4,) i32
    const int*   pt    = (const int*)d_in[3];     // (4,) i32
    float* out = (float*)d_out;
    unsigned* ws = (unsigned*)d_ws;

    k_fused<<<NBLK, 256, 0, stream>>>(masks, sf, pl, pt, ws, out);
}

// Round 9
// 300.539 us; speedup vs baseline: 2.1176x; 1.0663x over previous
//
#include <hip/hip_runtime.h>

// Problem constants (fixed by the reference module)
#define IMG_H 1024
#define IMG_W 1024
#define NPIX (IMG_H * IMG_W)
#define N_MASKS 32
#define N_WINDOWS 4
#define MPW 8          // N_MASKS / N_WINDOWS
#define WIN_H 512
#define WIN_W 512
#define SIM_THRESH 0.1f
#define NBLK 1024
#define MAGIC 0x13579BDFu

// Native 4-float vector for __builtin_nontemporal_store (HIP float4 is a class)
typedef float vf4 __attribute__((ext_vector_type(4)));

// ws layout (BYTE offsets — R8 bug was mixing word/byte units):
//   edges  @ byte   0 : 32 words — 8 border blocks x 4 partial masks (L,R,T,B)
//   bflag  @ byte 128 : 8 words — border-block done flags (MAGIC)
//   locg   @ byte 192 : 32 words — channel remap (block 8 of kernel A writes,
//                       kernel B reads across the kernel boundary)
//   ids    @ byte 1024: NPIX bytes of per-pixel argmax ids  (R8 had this at
//                       256, overlapping locg bytes 192..320 -> absmax 1.0)
// 0xAA poison != MAGIC => replay-safe without an init dispatch.
//
// Lessons encoded:
//  - R5: __launch_bounds__(256,4) forced VGPR=64 -> ~32 MB scratch spills.
//  - R6: ACQUIRE polls emit a cache-invalidate per poll -> chip-wide BW
//    collapse. Use RELAXED polls; RELEASE only on one-shot producer stores.
//  - R7: even with relaxed polls, 1024 consumer blocks parking mid-kernel
//    on a flag runs 165 us vs ~34 us of HBM traffic — all-block handshake
//    fusion is structurally bad. Only the 9-block handshake survives
//    (blocks 0..8 dispatch first => co-resident; block 8 is the sole
//    poller). Streaming blocks never touch flags.
//  - R8: ws layout overlap (locg/ids) — keep offsets in bytes, spaced.

#define WS_IDS_OFF 1024

__global__ __launch_bounds__(256) void k_argmax_loc(const float* __restrict__ masks,
                                                    const float* __restrict__ sf,
                                                    const int* __restrict__ pl,
                                                    const int* __restrict__ pt,
                                                    unsigned* __restrict__ ws,
                                                    unsigned char* __restrict__ ids) {
    unsigned* edges = ws;        // 32 words  @ byte 0
    unsigned* bflag = ws + 32;   // 8 words   @ byte 128
    unsigned* locg  = ws + 48;   // 32 words  @ byte 192..320

    __shared__ int spl[4], spt[4];
    __shared__ unsigned segmask[2];
    __shared__ float sfn[28 * 65];          // stride-65: no bank conflicts
    __shared__ unsigned step_word[512];     // ci | cj<<8 | hz<<16 | pass<<17
    __shared__ unsigned fedge[4];
    __shared__ int sP;

    const int tid = threadIdx.x;
    const int lane = tid & 63;
    const int wave = tid >> 6;
    const int b = blockIdx.x;

    if (tid < 4) { spl[tid] = pl[tid]; spt[tid] = pt[tid]; }
    if (tid < 2) segmask[tid] = 0u;
    __syncthreads();

    // ---------------- special duties (blocks 0..8 only) ----------------
    if (b < 8) {
        // Border duty: segments 2b, 2b+1. seg s: wi = s>>2, side = s&3 (L,R,T,B)
        for (int k = 0; k < 2; k++) {
            const int s = 2 * b + k;
            const int wi = s >> 2, side = s & 3;
            const int xs = max(spl[wi], 0), xe = min(spl[wi] + WIN_W, IMG_W);
            const int ys = max(spt[wi], 0), ye = min(spt[wi] + WIN_H, IMG_H);
            if (ys >= ye || xs >= xe) continue;
            const int L = (side < 2) ? (ye - ys) : (xe - xs);
            for (int u = tid; u < L; u += 256) {
                int x, y;
                if      (side == 0) { x = xs;     y = ys + u; }
                else if (side == 1) { x = xe - 1; y = ys + u; }
                else if (side == 2) { y = ys;     x = xs + u; }
                else                { y = ye - 1; x = xs + u; }
                const int p = y * IMG_W + x;
                float bv = masks[p];
                int bc = 0;
#pragma unroll
                for (int c = 1; c < N_MASKS; c++) {
                    const float v = masks[(size_t)c * NPIX + p];
                    if (v > bv) { bv = v; bc = c; }
                }
                if ((bc >> 3) == wi) atomicOr(&segmask[k], 1u << bc);
            }
        }
        __syncthreads();
        if (tid == 0) {
            unsigned e[4] = {0u, 0u, 0u, 0u};
            e[(2 * b) & 3]     |= segmask[0];
            e[(2 * b + 1) & 3] |= segmask[1];
#pragma unroll
            for (int i = 0; i < 4; i++)
                __hip_atomic_store(&edges[4 * b + i], e[i],
                                   __ATOMIC_RELAXED, __HIP_MEMORY_SCOPE_AGENT);
            __hip_atomic_store(&bflag[b], MAGIC,
                               __ATOMIC_RELEASE, __HIP_MEMORY_SCOPE_AGENT);
        }
    } else if (b == 8) {
        // Loc duty: sole poller. Wait for 8 border flags (RELAXED polls).
        if (tid < 8) {
            while (__hip_atomic_load(&bflag[tid], __ATOMIC_RELAXED,
                                     __HIP_MEMORY_SCOPE_AGENT) != MAGIC)
                __builtin_amdgcn_s_sleep(8);
        }
        __syncthreads();
        if (tid == 0) {
            unsigned e0 = 0, e1 = 0, e2 = 0, e3 = 0;
            for (int i = 0; i < 8; i++) {
                e0 |= __hip_atomic_load(&edges[4 * i + 0], __ATOMIC_RELAXED, __HIP_MEMORY_SCOPE_AGENT);
                e1 |= __hip_atomic_load(&edges[4 * i + 1], __ATOMIC_RELAXED, __HIP_MEMORY_SCOPE_AGENT);
                e2 |= __hip_atomic_load(&edges[4 * i + 2], __ATOMIC_RELAXED, __HIP_MEMORY_SCOPE_AGENT);
                e3 |= __hip_atomic_load(&edges[4 * i + 3], __ATOMIC_RELAXED, __HIP_MEMORY_SCOPE_AGENT);
            }
            fedge[0] = e0; fedge[1] = e1; fedge[2] = e2; fedge[3] = e3;
        }
        // normalize slot features: x / (||x|| + 1e-8), 4 waves x 7 rows
#pragma unroll
        for (int i = 0; i < 7; i++) {
            const int r = wave + 4 * i;
            const float v = sf[r * 64 + lane];
            float s2 = v * v;
#pragma unroll
            for (int off = 1; off < 64; off <<= 1) s2 += __shfl_xor(s2, off);
            sfn[r * 65 + lane] = v * (1.0f / (sqrtf(s2) + 1e-8f));
        }
        __syncthreads();
        if (tid == 0) {
            int lpl[4], lpt[4];
            for (int i = 0; i < 4; i++) { lpl[i] = spl[i]; lpt[i] = spt[i]; }
            int aI[8], aJ[8], aH[8], na = 0;
            for (int i = 0; i < N_WINDOWS; i++)
                for (int j = i + 1; j < N_WINDOWS; j++) {
                    if (lpt[i] == lpt[j] && abs(lpl[i] - lpl[j]) == WIN_W) {
                        if (lpl[i] < lpl[j]) { aI[na] = i; aJ[na] = j; }
                        else                 { aI[na] = j; aJ[na] = i; }
                        aH[na] = 1; na++;
                    }
                    if (lpl[i] == lpl[j] && abs(lpt[i] - lpt[j]) == WIN_H) {
                        if (lpt[i] < lpt[j]) { aI[na] = i; aJ[na] = j; }
                        else                 { aI[na] = j; aJ[na] = i; }
                        aH[na] = 0; na++;
                    }
                }
            int P = 0;
            for (int a = 0; a < na; a++)
                for (int ci = aI[a] * MPW + 1; ci < (aI[a] + 1) * MPW; ci++)
                    for (int cj = aJ[a] * MPW + 1; cj < (aJ[a] + 1) * MPW; cj++)
                        step_word[P++] = (unsigned)ci | ((unsigned)cj << 8)
                                       | ((unsigned)aH[a] << 16);
            sP = P;
        }
        __syncthreads();
        const int P = sP;
        {
            const unsigned gel = fedge[0], ger = fedge[1], get = fedge[2], geb = fedge[3];
            for (int p = tid; p < P; p += 256) {
                const unsigned w = step_word[p];
                const int ci = w & 255, cj = (w >> 8) & 255, hz = (w >> 16) & 1;
                const float* fi = &sfn[((ci >> 3) * (MPW - 1) + (ci & 7) - 1) * 65];
                const float* fj = &sfn[((cj >> 3) * (MPW - 1) + (cj & 7) - 1) * 65];
                float s = 0.f;
#pragma unroll
                for (int k2 = 0; k2 < 64; k2++) s += fi[k2] * fj[k2];
                const bool eok = hz ? (((ger >> ci) & 1u) && ((gel >> cj) & 1u))
                                    : (((geb >> ci) & 1u) && ((get >> cj) & 1u));
                if (eok && s > SIM_THRESH) step_word[p] = w | (1u << 17);
            }
        }
        __syncthreads();
        if (wave == 0) {
            unsigned merged = 0;
            int myloc = lane;
            for (int p = 0; p < P; p++) {
                const unsigned w = step_word[p];
                if (w >> 17) {
                    const int ci = w & 255, cj = (w >> 8) & 255;
                    if (!((merged >> ci) & 1u) && !((merged >> cj) & 1u)) {
                        const int keep = min(ci, cj), rem = max(ci, cj);
                        if (myloc == rem) myloc = keep;
                        merged |= 1u << rem;
                    }
                }
            }
            // Plain stores: kernel-boundary flush makes these visible to kernel B.
            if (lane < 32) locg[lane] = (unsigned)myloc;
        }
    }

    // ---------------- all blocks: row argmax -> ids (streaming read) ---------
    const int idx = (b * 256 + tid) * 4;    // exact fit: 1024 blocks x 1024 px
    float bv0, bv1, bv2, bv3;
    int bc0 = 0, bc1 = 0, bc2 = 0, bc3 = 0;
    {
        const float4 v = *(const float4*)(masks + idx);
        bv0 = v.x; bv1 = v.y; bv2 = v.z; bv3 = v.w;
    }
#pragma unroll
    for (int c = 1; c < N_MASKS; c++) {
        const float4 v = *(const float4*)(masks + (size_t)c * NPIX + idx);
        if (v.x > bv0) { bv0 = v.x; bc0 = c; }
        if (v.y > bv1) { bv1 = v.y; bc1 = c; }
        if (v.z > bv2) { bv2 = v.z; bc2 = c; }
        if (v.w > bv3) { bv3 = v.w; bc3 = c; }
    }
    *(uchar4*)(ids + idx) = make_uchar4((unsigned char)bc0, (unsigned char)bc1,
                                        (unsigned char)bc2, (unsigned char)bc3);
}

// Kernel B: pure streamer. out[c][p] = (loc[ids[p]] == c).
__global__ __launch_bounds__(256) void k_write(const unsigned char* __restrict__ ids,
                                               const unsigned* __restrict__ locg,
                                               float* __restrict__ out) {
    __shared__ int loc[32];
    if (threadIdx.x < 32) loc[threadIdx.x] = (int)locg[threadIdx.x];
    __syncthreads();

    const int idx = (blockIdx.x * 256 + threadIdx.x) * 4;   // exact fit
    const uchar4 id4 = *(const uchar4*)(ids + idx);
    const int r0 = loc[id4.x], r1 = loc[id4.y], r2 = loc[id4.z], r3 = loc[id4.w];
#pragma unroll
    for (int c = 0; c < N_MASKS; c++) {
        vf4 v;
        v.x = (r0 == c) ? 1.0f : 0.0f;
        v.y = (r1 == c) ? 1.0f : 0.0f;
        v.z = (r2 == c) ? 1.0f : 0.0f;
        v.w = (r3 == c) ? 1.0f : 0.0f;
        __builtin_nontemporal_store(v, (vf4*)(out + (size_t)c * NPIX + idx));
    }
}

extern "C" void kernel_launch(void* const* d_in, const int* in_sizes, int n_in,
                              void* d_out, int out_size, void* d_ws, size_t ws_size,
                              hipStream_t stream) {
    const float* masks = (const float*)d_in[0];   // (1, 32, 1024, 1024) f32
    const float* sf    = (const float*)d_in[1];   // (4, 7, 64) f32
    const int*   pl    = (const int*)d_in[2];     // (4,) i32
    const int*   pt    = (const int*)d_in[3];     // (4,) i32
    float* out = (float*)d_out;

    unsigned* ws = (unsigned*)d_ws;
    unsigned* locg = ws + 48;                              // byte 192
    unsigned char* ids = (unsigned char*)d_ws + WS_IDS_OFF; // byte 1024

    k_argmax_loc<<<NBLK, 256, 0, stream>>>(masks, sf, pl, pt, ws, ids);
    k_write<<<NBLK, 256, 0, stream>>>(ids, locg, out);
}